// Round 1
// baseline (802.702 us; speedup 1.0000x reference)
//
#include <hip/hip_runtime.h>

#define NTOK 8192
#define DIN  1024
#define DOUT 1024
#define HDIM 4096
#define NEXP 8
#define NPAIR (NTOK * 2)

typedef __attribute__((ext_vector_type(8))) short bf16x8;
typedef __attribute__((ext_vector_type(4))) float f32x4;

__device__ __forceinline__ unsigned short f2bf(float f) {
  union { float f; unsigned u; } v; v.f = f;
  unsigned u = v.u;
  unsigned r = (u + 0x7fffu + ((u >> 16) & 1u)) >> 16;  // RTNE
  return (unsigned short)r;
}

__device__ __forceinline__ void gload16(const void* g, void* l) {
  __builtin_amdgcn_global_load_lds(
      (const __attribute__((address_space(1))) unsigned int*)g,
      (__attribute__((address_space(3))) unsigned int*)l, 16, 0, 0);
}

// ---------------- gate: fp64 dot, scores over 8 hypercube corners, top-2 ----
__global__ void gate_kernel(const float* __restrict__ x, const float* __restrict__ Wg,
                            int* __restrict__ cnt, int* __restrict__ ptok,
                            float* __restrict__ pw) {
  const int lane = threadIdx.x & 63;
  const int t = blockIdx.x * 4 + (threadIdx.x >> 6);
  const float* xr = x + (size_t)t * DIN + lane * 16;
  const float* wr = Wg + (size_t)lane * 16 * 3;
  double d0 = 0, d1 = 0, d2 = 0;
#pragma unroll
  for (int j = 0; j < 16; j++) {
    double xv = xr[j];
    d0 += xv * wr[j * 3 + 0];
    d1 += xv * wr[j * 3 + 1];
    d2 += xv * wr[j * 3 + 2];
  }
#pragma unroll
  for (int o = 32; o > 0; o >>= 1) {
    d0 += __shfl_down(d0, o);
    d1 += __shfl_down(d1, o);
    d2 += __shfl_down(d2, o);
  }
  if (lane == 0) {
    double l0 = d0 > 0 ? d0 : 0, l1 = d1 > 0 ? d1 : 0, l2 = d2 > 0 ? d2 : 0;
    double s[NEXP];
#pragma unroll
    for (int e = 0; e < NEXP; e++)
      s[e] = ((e & 1) ? l0 : -l0) + ((e & 2) ? l1 : -l1) + ((e & 4) ? l2 : -l2);
    int e0 = 0;
    for (int e = 1; e < NEXP; e++) if (s[e] > s[e0]) e0 = e;        // ties -> lowest idx
    int e1 = -1;
    for (int e = 0; e < NEXP; e++) { if (e == e0) continue; if (e1 < 0 || s[e] > s[e1]) e1 = e; }
    double w0 = 1.0 / (1.0 + exp(s[e1] - s[e0]));  // == renormalized softmax pair
    double w1 = 1.0 - w0;
    int p0 = atomicAdd(cnt + e0, 1);
    ptok[e0 * NTOK + p0] = t; pw[e0 * NTOK + p0] = (float)w0;
    int p1 = atomicAdd(cnt + e1, 1);
    ptok[e1 * NTOK + p1] = t; pw[e1 * NTOK + p1] = (float)w1;
  }
}

__global__ void scan_kernel(const int* __restrict__ cnt, int* __restrict__ off) {
  if (threadIdx.x == 0) {
    int a = 0;
    for (int e = 0; e < NEXP; e++) { off[e] = a; a += cnt[e]; }
  }
}

// ---------------- fp32 -> bf16 elementwise --------------------------------
__global__ void cvt_bf16_kernel(const float* __restrict__ src,
                                unsigned short* __restrict__ dst, int n) {
  int i = (blockIdx.x * 256 + threadIdx.x) * 8;
  if (i >= n) return;
  float4 a = *(const float4*)(src + i);
  float4 b = *(const float4*)(src + i + 4);
  __align__(16) unsigned short t[8] = {f2bf(a.x), f2bf(a.y), f2bf(a.z), f2bf(a.w),
                                       f2bf(b.x), f2bf(b.y), f2bf(b.z), f2bf(b.w)};
  *(uint4*)(dst + i) = *(const uint4*)t;
}

// ---------------- fp32 [e][K][N] -> bf16 [e][N][K] transpose ---------------
__global__ void transpose_cvt(const float* __restrict__ src,
                              unsigned short* __restrict__ dst, int K, int N) {
  __shared__ float tile[64][65];
  const size_t base = (size_t)blockIdx.z * K * N;
  const float* s = src + base;
  unsigned short* d = dst + base;
  int n0 = blockIdx.x * 64, k0 = blockIdx.y * 64;
  for (int idx = threadIdx.x; idx < 64 * 16; idx += 256) {
    int r = idx >> 4, c4 = (idx & 15) * 4;
    float4 v = *(const float4*)(s + (size_t)(k0 + r) * N + n0 + c4);
    tile[r][c4 + 0] = v.x; tile[r][c4 + 1] = v.y;
    tile[r][c4 + 2] = v.z; tile[r][c4 + 3] = v.w;
  }
  __syncthreads();
  for (int idx = threadIdx.x; idx < 64 * 8; idx += 256) {
    int nl = idx >> 3, c8 = (idx & 7) * 8;
    __align__(16) unsigned short tmp[8];
#pragma unroll
    for (int j = 0; j < 8; j++) tmp[j] = f2bf(tile[c8 + j][nl]);
    *(uint4*)(d + (size_t)(n0 + nl) * K + k0 + c8) = *(const uint4*)tmp;
  }
}

// ---------------- grouped GEMM1: h = relu(x @ W1[e] + b1[e]) ---------------
__global__ __launch_bounds__(256, 2) void gemm1_kernel(
    const unsigned short* __restrict__ xbf,   // [NTOK][DIN]
    const unsigned short* __restrict__ w1t,   // [E][HDIM][DIN]
    const float* __restrict__ b1,             // [E][HDIM]
    const int* __restrict__ cnt, const int* __restrict__ off,
    const int* __restrict__ ptok,
    unsigned short* __restrict__ h)           // [NPAIR][HDIM]
{
  const int e = blockIdx.z;
  const int ce = cnt[e];
  const int m0 = blockIdx.y * 128;
  if (m0 >= ce) return;
  const int n0 = blockIdx.x * 128;
  const int oe = off[e];
  __shared__ __align__(16) unsigned short lA[128 * 32];
  __shared__ __align__(16) unsigned short lB[128 * 32];
  const int tid = threadIdx.x;
  const int lane = tid & 63;
  const int wv = tid >> 6;
  const int wr = wv >> 1, wc = wv & 1;

  const int c0 = tid, c1 = tid + 256;
  const int ra0 = c0 >> 2, ra1 = c1 >> 2;
  const int ka0 = (c0 & 3) * 8, ka1 = (c1 & 3) * 8;
  const int ta0 = ptok[e * NTOK + min(m0 + ra0, ce - 1)];
  const int ta1 = ptok[e * NTOK + min(m0 + ra1, ce - 1)];
  const unsigned short* ga0 = xbf + (size_t)ta0 * DIN + ka0;
  const unsigned short* ga1 = xbf + (size_t)ta1 * DIN + ka1;
  const unsigned short* wb = w1t + (size_t)e * HDIM * DIN;
  const unsigned short* gb0 = wb + (size_t)(n0 + ra0) * DIN + ka0;
  const unsigned short* gb1 = wb + (size_t)(n0 + ra1) * DIN + ka1;
  unsigned short* lA0 = lA + c0 * 8;
  unsigned short* lA1 = lA + c1 * 8;
  unsigned short* lB0 = lB + c0 * 8;
  unsigned short* lB1 = lB + c1 * 8;

  f32x4 acc[4][4] = {};
  const int fr = lane & 15;
  const int fk = (lane >> 4) * 8;

  for (int k0 = 0; k0 < DIN; k0 += 32) {
    __syncthreads();
    gload16(ga0 + k0, lA0);
    gload16(ga1 + k0, lA1);
    gload16(gb0 + k0, lB0);
    gload16(gb1 + k0, lB1);
    asm volatile("s_waitcnt vmcnt(0)" ::: "memory");
    __syncthreads();
    bf16x8 a[4], b[4];
#pragma unroll
    for (int i = 0; i < 4; i++)
      a[i] = *(const bf16x8*)(lA + ((wr * 64 + i * 16 + fr) * 32 + fk));
#pragma unroll
    for (int i = 0; i < 4; i++)
      b[i] = *(const bf16x8*)(lB + ((wc * 64 + i * 16 + fr) * 32 + fk));
#pragma unroll
    for (int mi = 0; mi < 4; mi++)
#pragma unroll
      for (int ni = 0; ni < 4; ni++)
        acc[mi][ni] = __builtin_amdgcn_mfma_f32_16x16x32_bf16(a[mi], b[ni], acc[mi][ni], 0, 0, 0);
  }

  const int cr = (lane >> 4) * 4;
  const int cc = lane & 15;
#pragma unroll
  for (int mi = 0; mi < 4; mi++) {
    int rbase = wr * 64 + mi * 16 + cr;
#pragma unroll
    for (int r = 0; r < 4; r++) {
      int grow = m0 + rbase + r;
      if (grow >= ce) continue;
      size_t hoff = (size_t)(oe + grow) * HDIM;
#pragma unroll
      for (int ni = 0; ni < 4; ni++) {
        int col = n0 + wc * 64 + ni * 16 + cc;
        float v = acc[mi][ni][r] + b1[e * HDIM + col];
        h[hoff + col] = f2bf(v > 0.f ? v : 0.f);
      }
    }
  }
}

// ---------------- grouped GEMM2: out += w * (h @ W2[e] + b2[e]) ------------
__global__ __launch_bounds__(256, 2) void gemm2_kernel(
    const unsigned short* __restrict__ h,     // [NPAIR][HDIM]
    const unsigned short* __restrict__ w2t,   // [E][DOUT][HDIM]
    const float* __restrict__ b2,             // [E][DOUT]
    const int* __restrict__ cnt, const int* __restrict__ off,
    const int* __restrict__ ptok, const float* __restrict__ pw,
    float* __restrict__ out)                  // [NTOK][DOUT]
{
  const int e = blockIdx.z;
  const int ce = cnt[e];
  const int m0 = blockIdx.y * 128;
  if (m0 >= ce) return;
  const int n0 = blockIdx.x * 128;
  const int oe = off[e];
  __shared__ __align__(16) unsigned short lA[128 * 32];
  __shared__ __align__(16) unsigned short lB[128 * 32];
  const int tid = threadIdx.x;
  const int lane = tid & 63;
  const int wv = tid >> 6;
  const int wr = wv >> 1, wc = wv & 1;

  const int c0 = tid, c1 = tid + 256;
  const int ra0 = c0 >> 2, ra1 = c1 >> 2;
  const int ka0 = (c0 & 3) * 8, ka1 = (c1 & 3) * 8;
  const int rc0 = min(m0 + ra0, ce - 1), rc1 = min(m0 + ra1, ce - 1);
  const unsigned short* ga0 = h + (size_t)(oe + rc0) * HDIM + ka0;
  const unsigned short* ga1 = h + (size_t)(oe + rc1) * HDIM + ka1;
  const unsigned short* wb = w2t + (size_t)e * DOUT * HDIM;
  const unsigned short* gb0 = wb + (size_t)(n0 + ra0) * HDIM + ka0;
  const unsigned short* gb1 = wb + (size_t)(n0 + ra1) * HDIM + ka1;
  unsigned short* lA0 = lA + c0 * 8;
  unsigned short* lA1 = lA + c1 * 8;
  unsigned short* lB0 = lB + c0 * 8;
  unsigned short* lB1 = lB + c1 * 8;

  f32x4 acc[4][4] = {};
  const int fr = lane & 15;
  const int fk = (lane >> 4) * 8;

  for (int k0 = 0; k0 < HDIM; k0 += 32) {
    __syncthreads();
    gload16(ga0 + k0, lA0);
    gload16(ga1 + k0, lA1);
    gload16(gb0 + k0, lB0);
    gload16(gb1 + k0, lB1);
    asm volatile("s_waitcnt vmcnt(0)" ::: "memory");
    __syncthreads();
    bf16x8 a[4], b[4];
#pragma unroll
    for (int i = 0; i < 4; i++)
      a[i] = *(const bf16x8*)(lA + ((wr * 64 + i * 16 + fr) * 32 + fk));
#pragma unroll
    for (int i = 0; i < 4; i++)
      b[i] = *(const bf16x8*)(lB + ((wc * 64 + i * 16 + fr) * 32 + fk));
#pragma unroll
    for (int mi = 0; mi < 4; mi++)
#pragma unroll
      for (int ni = 0; ni < 4; ni++)
        acc[mi][ni] = __builtin_amdgcn_mfma_f32_16x16x32_bf16(a[mi], b[ni], acc[mi][ni], 0, 0, 0);
  }

  const int cr = (lane >> 4) * 4;
  const int cc = lane & 15;
#pragma unroll
  for (int mi = 0; mi < 4; mi++) {
    int rbase = wr * 64 + mi * 16 + cr;
#pragma unroll
    for (int r = 0; r < 4; r++) {
      int grow = m0 + rbase + r;
      if (grow >= ce) continue;
      int idx = e * NTOK + grow;
      int token = ptok[idx];
      float w = pw[idx];
#pragma unroll
      for (int ni = 0; ni < 4; ni++) {
        int col = n0 + wc * 64 + ni * 16 + cc;
        float v = (acc[mi][ni][r] + b2[e * DOUT + col]) * w;
        atomicAdd(out + (size_t)token * DOUT + col, v);
      }
    }
  }
}

extern "C" void kernel_launch(void* const* d_in, const int* in_sizes, int n_in,
                              void* d_out, int out_size, void* d_ws, size_t ws_size,
                              hipStream_t stream) {
  const float* x  = (const float*)d_in[0];
  const float* Wg = (const float*)d_in[1];
  const float* W1 = (const float*)d_in[2];
  const float* b1 = (const float*)d_in[3];
  const float* W2 = (const float*)d_in[4];
  const float* b2 = (const float*)d_in[5];
  float* out = (float*)d_out;

  char* ws = (char*)d_ws;
  size_t o = 0;
  auto nxt = [&](size_t b) { char* p = ws + o; o = (o + b + 255) & ~(size_t)255; return p; };
  int* cnt = (int*)nxt(64);
  int* off = (int*)nxt(64);
  int* ptok = (int*)nxt((size_t)NEXP * NTOK * 4);
  float* pw = (float*)nxt((size_t)NEXP * NTOK * 4);
  unsigned short* xbf = (unsigned short*)nxt((size_t)NTOK * DIN * 2);
  unsigned short* w1t = (unsigned short*)nxt((size_t)NEXP * HDIM * DIN * 2);
  unsigned short* w2t = (unsigned short*)nxt((size_t)NEXP * DOUT * HDIM * 2);
  unsigned short* hbuf = (unsigned short*)nxt((size_t)NPAIR * HDIM * 2);

  hipMemsetAsync(cnt, 0, 64, stream);
  hipMemsetAsync(out, 0, (size_t)NTOK * DOUT * 4, stream);

  gate_kernel<<<NTOK / 4, 256, 0, stream>>>(x, Wg, cnt, ptok, pw);
  scan_kernel<<<1, 64, 0, stream>>>(cnt, off);
  cvt_bf16_kernel<<<(NTOK * DIN / 8) / 256, 256, 0, stream>>>(x, xbf, NTOK * DIN);
  transpose_cvt<<<dim3(HDIM / 64, DIN / 64, NEXP), 256, 0, stream>>>(W1, w1t, DIN, HDIM);
  transpose_cvt<<<dim3(DOUT / 64, HDIM / 64, NEXP), 256, 0, stream>>>(W2, w2t, HDIM, DOUT);

  gemm1_kernel<<<dim3(HDIM / 128, NTOK / 128, NEXP), 256, 0, stream>>>(
      xbf, w1t, b1, cnt, off, ptok, hbuf);
  gemm2_kernel<<<dim3(DOUT / 128, NTOK / 128, NEXP), 256, 0, stream>>>(
      hbuf, w2t, b2, cnt, off, ptok, pw, out);
}